// Round 2
// baseline (375.634 us; speedup 1.0000x reference)
//
#include <hip/hip_runtime.h>
#include <math.h>

#define S_LEN 1024
#define BATCH 8
#define NH 8
#define QD 32
#define PD 4
#define EMB 512
#define NPROJ 544
#define LPOS 2047  // 2*S-1

typedef __attribute__((ext_vector_type(8))) short short8;   // 8 bf16 = 4 VGPR
typedef __attribute__((ext_vector_type(4))) float f32x4;
typedef __attribute__((ext_vector_type(4))) unsigned int u32x4;
typedef __attribute__((ext_vector_type(2))) unsigned int u32x2;

union U4 { u32x4 u; short8 s; };

// fp32 -> bf16 round-to-nearest-even
static __device__ inline unsigned short f2bf(float f) {
    unsigned int u = __builtin_bit_cast(unsigned int, f);
    u += 0x7fffu + ((u >> 16) & 1u);
    return (unsigned short)(u >> 16);
}

// ---------------------------------------------------------------------------
// Kernel 0 (merged): blocks [0,4368) convert X/W f32->bf16;
//                    blocks [4368,4624) compute PE and store reversed bf16.
// ---------------------------------------------------------------------------
#define NXV 1048576   // X float4 count
#define NWV 69632     // W float4 count
#define CONV_BLOCKS 4368
__global__ __launch_bounds__(256) void prep_kernel(
    const float* __restrict__ X, const float* __restrict__ W,
    const float* __restrict__ pos, const float* __restrict__ Wp,
    unsigned short* __restrict__ Xb, unsigned short* __restrict__ Wb,
    unsigned short* __restrict__ PEr)
{
    const int bx = blockIdx.x;
    if (bx < CONV_BLOCKS) {
        int idx = bx * 256 + threadIdx.x;
        const f32x4* src;
        unsigned short* dst;
        int i;
        if (idx < NXV)            { src = (const f32x4*)X; dst = Xb; i = idx; }
        else if (idx < NXV + NWV) { src = (const f32x4*)W; dst = Wb; i = idx - NXV; }
        else return;
        f32x4 v = src[i];
        union { unsigned short s[4]; u32x2 u; } pk;
        pk.s[0] = f2bf(v.x); pk.s[1] = f2bf(v.y);
        pk.s[2] = f2bf(v.z); pk.s[3] = f2bf(v.w);
        ((u32x2*)dst)[i] = pk.u;
    } else {
        // PE[l][ht] = dot(pos[l], Wp[ht]); PEr[h][w][t] = bf16(PE[2046-w][h*4+t])
        int o = (bx - CONV_BLOCKS) * 256 + threadIdx.x;
        if (o >= LPOS * 32) return;
        int l = o >> 5, ht = o & 31;
        const f32x4* pr = (const f32x4*)(pos + (size_t)l * 192);
        const f32x4* wr = (const f32x4*)(Wp + (size_t)ht * 192);
        float acc = 0.0f;
#pragma unroll 8
        for (int d = 0; d < 48; ++d) {
            f32x4 a = pr[d], w = wr[d];
            acc += a.x * w.x + a.y * w.y + a.z * w.z + a.w * w.w;
        }
        int h = ht >> 2, t = ht & 3, w = 2046 - l;
        PEr[((size_t)h * LPOS + w) * PD + t] = f2bf(acc);
    }
}

// ---------------------------------------------------------------------------
// Kernel 1: proj^T = W(544x512) @ X^T(512x8192) via MFMA.
// W o-tile staged in LDS (2 k-phases of 256), conflict-free padded rows.
// Block 256 (4 waves): tile 64 o x 64 m; wave wv: 16 m-rows, 4 o-subtiles.
// ---------------------------------------------------------------------------
#define WROW 264   // shorts per LDS W row (256 data + 8 pad): 528 B, 16B-aligned,
                   // row step 132 words -> +4 banks/row -> 2-way on b128 (free)
__global__ __launch_bounds__(256) void proj_kernel(
    const unsigned short* __restrict__ Xb, const unsigned short* __restrict__ Wb,
    const float* __restrict__ bias,
    unsigned short* __restrict__ Qb, unsigned short* __restrict__ Kb,
    unsigned short* __restrict__ Pb)
{
    __shared__ unsigned short wlds[64 * WROW];   // 33,792 B

    const int tid = threadIdx.x;
    const int wv = tid >> 6, lane = tid & 63;
    const int n16 = lane & 15, quad = lane >> 4;
    const int m0 = blockIdx.x * 64, o0 = blockIdx.y * 64;
    const int m = m0 + wv * 16 + n16;
    const unsigned short* xrow = Xb + (size_t)m * EMB;

    f32x4 acc[4] = {{0,0,0,0},{0,0,0,0},{0,0,0,0},{0,0,0,0}};

#pragma unroll
    for (int phase = 0; phase < 2; ++phase) {
        __syncthreads();   // previous phase fully consumed
#pragma unroll
        for (int u = 0; u < 8; ++u) {
            int idx = tid + 256 * u;          // 0..2047
            int r = idx >> 5, c = idx & 31;   // row, 16B chunk within 512B half-row
            int o = o0 + r; if (o > NPROJ - 1) o = NPROJ - 1;
            u32x4 v = *(const u32x4*)(Wb + (size_t)o * EMB + phase * 256 + c * 8);
            *(u32x4*)(wlds + r * WROW + c * 8) = v;
        }
        __syncthreads();
#pragma unroll
        for (int kk = 0; kk < 8; ++kk) {
            const int k0 = kk * 32;
            U4 bx; bx.u = *(const u32x4*)(xrow + phase * 256 + k0 + quad * 8);
#pragma unroll
            for (int ot = 0; ot < 4; ++ot) {
                U4 aw; aw.u = *(const u32x4*)(wlds + (ot * 16 + n16) * WROW + k0 + quad * 8);
                acc[ot] = __builtin_amdgcn_mfma_f32_16x16x32_bf16(aw.s, bx.s, acc[ot], 0, 0, 0);
            }
        }
    }

    const int s = m >> 3, b = m & 7;
#pragma unroll
    for (int ot = 0; ot < 4; ++ot) {
        int obase = o0 + ot * 16 + quad * 4;   // 4 consecutive o per lane
        if (obase >= NPROJ) continue;
        f32x4 bv = *(const f32x4*)(bias + obase);
        union { unsigned short sh[4]; u32x2 u; } pk;
        pk.sh[0] = f2bf(acc[ot].x + bv.x);
        pk.sh[1] = f2bf(acc[ot].y + bv.y);
        pk.sh[2] = f2bf(acc[ot].z + bv.z);
        pk.sh[3] = f2bf(acc[ot].w + bv.w);
        unsigned short* dst;
        if (obase < 256) {
            int h = obase >> 5, d = obase & 31;
            dst = Qb + (((size_t)(h * BATCH + b)) * S_LEN + s) * QD + d;
        } else if (obase < 512) {
            int o2 = obase - 256;
            int h = o2 >> 5, d = o2 & 31;
            dst = Kb + (((size_t)(h * BATCH + b)) * S_LEN + s) * QD + d;
        } else {
            int h = (obase - 512) >> 2;
            dst = Pb + (((size_t)(h * BATCH + b)) * S_LEN + s) * PD;
        }
        *(u32x2*)dst = pk.u;
    }
}

// ---------------------------------------------------------------------------
// Kernel 2: scores^T via MFMA + Toeplitz pos-fold + mask + softmax + write.
// Grid (S/32, H*B). Block 256 = 4 waves; wave wv covers j in [wv*256, +256).
// Each block handles 32 i-rows as TWO sequential 16-row groups sharing the
// staged PE window and mask array (halves per-block prologue overhead vs
// 16-row blocks). Group g's PE indices are group 0's + 16 (Toeplitz shift).
// C^T tile: lane holds row i = i0 + g*16 + (lane&15), cols j0+quad*4+{0..3}.
// launch_bounds (256,3): (256,4) forced 128-VGPR cap -> spills, −16us (R1).
// ---------------------------------------------------------------------------
__global__ __launch_bounds__(256, 3) void attn_kernel(
    const unsigned short* __restrict__ Qb, const unsigned short* __restrict__ Kb,
    const unsigned short* __restrict__ Pb, const u32x2* __restrict__ PEr,
    const unsigned char* __restrict__ mask, float* __restrict__ out)
{
    __shared__ u32x4 pe_pair[1056];     // {PE4[w], PE4[w+1]} bf16, 16 B/slot
    __shared__ float madd[S_LEN];
    __shared__ float redm[4][16];
    __shared__ float reds[4][16];

    const int hb = blockIdx.y;
    const int h = hb >> 3, b = hb & 7;
    const int i0 = blockIdx.x * 32;
    const int tid = threadIdx.x;
    const int wv = tid >> 6, lane = tid & 63;
    const int n16 = lane & 15, quad = lane >> 4;

    // stage reversed-PE pair window: pe_pair[w] = {PE4r[i0+w], PE4r[i0+w+1]}
    // Max consumed slot = 1053 (group 1, wbase max 1045, +8); its hi element
    // is PEr4[i0+1054] <= index 2046 (valid). Stage [0,1054).
    const u32x2* src = PEr + (size_t)h * LPOS + i0;
    for (int wl = tid; wl < 1054; wl += 256) {
        u32x2 lo = src[wl];
        u32x2 hi = src[wl + 1];
        u32x4 v; v.x = lo.x; v.y = lo.y; v.z = hi.x; v.w = hi.y;
        pe_pair[wl] = v;
    }
    for (int j = tid; j < S_LEN; j += 256)
        madd[j] = mask[b * S_LEN + j] ? -INFINITY : 0.0f;

    __syncthreads();

    const unsigned short* kbase =
        Kb + (size_t)hb * S_LEN * QD + (size_t)(wv * 256 + n16) * QD + quad * 8;

#pragma unroll 1
    for (int g = 0; g < 2; ++g) {
        const int irow = i0 + g * 16 + n16;
        // B1: Q fragment (row irow, k = quad*8..+7)
        U4 b1; b1.u = *(const u32x4*)(Qb + ((size_t)hb * S_LEN + irow) * QD + quad * 8);
        // P row -> sparse B-frags for the two pos MFMAs
        u32x2 p4 = *(const u32x2*)(Pb + ((size_t)hb * S_LEN + irow) * PD);
        U4 b2, b3;
        b2.u.x = (n16 == 2 * quad)     ? p4.x : 0u;
        b2.u.y = (n16 == 2 * quad)     ? p4.y : 0u;
        b2.u.z = (n16 == 2 * quad + 1) ? p4.x : 0u;
        b2.u.w = (n16 == 2 * quad + 1) ? p4.y : 0u;
        b3.u.x = (n16 == 2 * quad + 8) ? p4.x : 0u;
        b3.u.y = (n16 == 2 * quad + 8) ? p4.y : 0u;
        b3.u.z = (n16 == 2 * quad + 9) ? p4.x : 0u;
        b3.u.w = (n16 == 2 * quad + 9) ? p4.y : 0u;

        f32x4 sc[16];
        const int wbase = 1023 - wv * 256 - n16 + 2 * quad + g * 16;

        // waves run this loop un-barriered; resident waves sit at different
        // phases (load vs MFMA vs store) -> setprio pays here (m191 regime)
        __builtin_amdgcn_s_setprio(1);
#pragma unroll
        for (int t = 0; t < 16; ++t) {
            U4 a1; a1.u = *(const u32x4*)(kbase + t * 16 * QD);
            U4 a2; a2.u = pe_pair[wbase - t * 16];
            U4 a3; a3.u = pe_pair[wbase - t * 16 + 8];
            f32x4 acc = {0.0f, 0.0f, 0.0f, 0.0f};
            acc = __builtin_amdgcn_mfma_f32_16x16x32_bf16(a3.s, b3.s, acc, 0, 0, 0);
            acc = __builtin_amdgcn_mfma_f32_16x16x32_bf16(a2.s, b2.s, acc, 0, 0, 0);
            acc = __builtin_amdgcn_mfma_f32_16x16x32_bf16(a1.s, b1.s, acc, 0, 0, 0);
            sc[t] = acc + *(const f32x4*)&madd[wv * 256 + t * 16 + quad * 4];
        }
        __builtin_amdgcn_s_setprio(0);

        // softmax over j for row irow (lane holds only this row)
        float mx = -INFINITY;
#pragma unroll
        for (int t = 0; t < 16; ++t)
            mx = fmaxf(mx, fmaxf(fmaxf(sc[t].x, sc[t].y), fmaxf(sc[t].z, sc[t].w)));
        mx = fmaxf(mx, __shfl_xor(mx, 16));
        mx = fmaxf(mx, __shfl_xor(mx, 32));
        if (quad == 0) redm[wv][n16] = mx;
        __syncthreads();
        mx = fmaxf(fmaxf(redm[0][n16], redm[1][n16]),
                   fmaxf(redm[2][n16], redm[3][n16]));

        float sum = 0.0f;
#pragma unroll
        for (int t = 0; t < 16; ++t) {
            sc[t].x = __expf(sc[t].x - mx);
            sc[t].y = __expf(sc[t].y - mx);
            sc[t].z = __expf(sc[t].z - mx);
            sc[t].w = __expf(sc[t].w - mx);
            sum += sc[t].x + sc[t].y + sc[t].z + sc[t].w;
        }
        sum += __shfl_xor(sum, 16);
        sum += __shfl_xor(sum, 32);
        if (quad == 0) reds[wv][n16] = sum;
        __syncthreads();
        const float tot = reds[0][n16] + reds[1][n16] + reds[2][n16] + reds[3][n16];
        const float inv = 1.0f / tot;

        float* orow = out + ((size_t)hb * S_LEN + irow) * S_LEN;
#pragma unroll
        for (int t = 0; t < 16; ++t) {
            const int j0 = wv * 256 + t * 16 + quad * 4;
            f32x4 o4 = sc[t] * inv;
            __builtin_nontemporal_store(o4, (f32x4*)(orow + j0));
        }
        // next group writes redm only after this barrier-protected read of reds
    }
}

// ---------------------------------------------------------------------------
extern "C" void kernel_launch(void* const* d_in, const int* in_sizes, int n_in,
                              void* d_out, int out_size, void* d_ws, size_t ws_size,
                              hipStream_t stream) {
    (void)in_sizes; (void)n_in; (void)out_size; (void)ws_size;
    const float* x           = (const float*)d_in[0];
    const float* pos_emb     = (const float*)d_in[1];
    const unsigned char* msk = (const unsigned char*)d_in[2];
    const float* in_proj_w   = (const float*)d_in[3];
    const float* in_proj_b   = (const float*)d_in[4];
    const float* linear_posw = (const float*)d_in[5];
    float* out = (float*)d_out;

    char* p = (char*)d_ws;
    unsigned short* Qb  = (unsigned short*)p; p += (size_t)4 << 20;  // 4 MB
    unsigned short* Kb  = (unsigned short*)p; p += (size_t)4 << 20;  // 4 MB
    unsigned short* Pb  = (unsigned short*)p; p += 524288;           // 0.5 MB
    unsigned short* PEr = (unsigned short*)p; p += 131072;           // 128 KB
    unsigned short* Xb  = (unsigned short*)p; p += (size_t)8 << 20;  // 8 MB
    unsigned short* Wb  = (unsigned short*)p; p += 557056;           // ~0.53 MB

    prep_kernel<<<4624, 256, 0, stream>>>(x, in_proj_w, pos_emb, linear_posw, Xb, Wb, PEr);
    proj_kernel<<<dim3(128, 9), 256, 0, stream>>>(Xb, Wb, in_proj_b, Qb, Kb, Pb);
    attn_kernel<<<dim3(32, 64), 256, 0, stream>>>(Qb, Kb, Pb, (const u32x2*)PEr, msk, out);
}

// Round 3
// 348.952 us; speedup vs baseline: 1.0765x; 1.0765x over previous
//
#include <hip/hip_runtime.h>
#include <math.h>

#define S_LEN 1024
#define BATCH 8
#define NH 8
#define QD 32
#define PD 4
#define EMB 512
#define NPROJ 544
#define LPOS 2047  // 2*S-1

typedef __attribute__((ext_vector_type(8))) short short8;   // 8 bf16 = 4 VGPR
typedef __attribute__((ext_vector_type(4))) float f32x4;
typedef __attribute__((ext_vector_type(4))) unsigned int u32x4;
typedef __attribute__((ext_vector_type(2))) unsigned int u32x2;

union U4 { u32x4 u; short8 s; };

// fp32 -> bf16 round-to-nearest-even
static __device__ inline unsigned short f2bf(float f) {
    unsigned int u = __builtin_bit_cast(unsigned int, f);
    u += 0x7fffu + ((u >> 16) & 1u);
    return (unsigned short)(u >> 16);
}

// ---------------------------------------------------------------------------
// Kernel 0: convert X (4,194,304 f32) and W (278,528 f32) to bf16.
// 2 f32x4 per thread -> one 16B store each.
// ---------------------------------------------------------------------------
#define NXV 1048576   // X float4 count
#define NWV 69632     // W float4 count
__global__ __launch_bounds__(256) void convert_kernel(
    const float* __restrict__ X, const float* __restrict__ W,
    unsigned short* __restrict__ Xb, unsigned short* __restrict__ Wb)
{
    int idx = blockIdx.x * 256 + threadIdx.x;
    int i = idx * 2;   // NXV is even: a pair never straddles the X/W boundary
    const f32x4* src;
    unsigned short* dst;
    if (i < NXV)            { src = (const f32x4*)X; dst = Xb; }
    else if (i < NXV + NWV) { src = (const f32x4*)W; dst = Wb; i -= NXV; }
    else return;
    f32x4 v0 = src[i], v1 = src[i + 1];
    union { unsigned short s[8]; u32x4 u; } pk;
    pk.s[0] = f2bf(v0.x); pk.s[1] = f2bf(v0.y);
    pk.s[2] = f2bf(v0.z); pk.s[3] = f2bf(v0.w);
    pk.s[4] = f2bf(v1.x); pk.s[5] = f2bf(v1.y);
    pk.s[6] = f2bf(v1.z); pk.s[7] = f2bf(v1.w);
    ((u32x4*)dst)[i >> 1] = pk.u;
}

// ---------------------------------------------------------------------------
// Kernel 1: proj^T = W(544x512) @ X^T(512x8192) via MFMA.
// W o-tile staged in LDS (2 k-phases of 256), conflict-free padded rows.
// Block 256 (4 waves): tile 64 o x 128 m; wave wv: 32 m-rows (2 groups of 16),
// 4 o-subtiles -> 8 MFMAs per kk, each LDS aw read feeds 2 MFMAs.
// vs 64x64 tile: halves W L2 traffic + barriers per FLOP.
// ---------------------------------------------------------------------------
#define WROW 264   // shorts per LDS W row (256 data + 8 pad): 528 B, 16B-aligned,
                   // row step 132 words -> +4 banks/row -> 2-way on b128 (free)
__global__ __launch_bounds__(256) void proj_kernel(
    const unsigned short* __restrict__ Xb, const unsigned short* __restrict__ Wb,
    const float* __restrict__ bias,
    unsigned short* __restrict__ Qb, unsigned short* __restrict__ Kb,
    unsigned short* __restrict__ Pb)
{
    __shared__ unsigned short wlds[64 * WROW];   // 33,792 B

    const int tid = threadIdx.x;
    const int wv = tid >> 6, lane = tid & 63;
    const int n16 = lane & 15, quad = lane >> 4;
    const int m0 = blockIdx.x * 128, o0 = blockIdx.y * 64;
    const int mrow = m0 + wv * 32 + n16;          // group g adds +16
    const unsigned short* xrow = Xb + (size_t)mrow * EMB;

    f32x4 acc[2][4] = {{{0,0,0,0},{0,0,0,0},{0,0,0,0},{0,0,0,0}},
                       {{0,0,0,0},{0,0,0,0},{0,0,0,0},{0,0,0,0}}};

#pragma unroll
    for (int phase = 0; phase < 2; ++phase) {
        __syncthreads();   // previous phase fully consumed
#pragma unroll
        for (int u = 0; u < 8; ++u) {
            int idx = tid + 256 * u;          // 0..2047
            int r = idx >> 5, c = idx & 31;   // row, 16B chunk within 512B half-row
            int o = o0 + r; if (o > NPROJ - 1) o = NPROJ - 1;
            u32x4 v = *(const u32x4*)(Wb + (size_t)o * EMB + phase * 256 + c * 8);
            *(u32x4*)(wlds + r * WROW + c * 8) = v;
        }
        __syncthreads();
#pragma unroll
        for (int kk = 0; kk < 8; ++kk) {
            const int k0 = kk * 32;
            U4 bx0; bx0.u = *(const u32x4*)(xrow + phase * 256 + k0 + quad * 8);
            U4 bx1; bx1.u = *(const u32x4*)(xrow + (size_t)16 * EMB + phase * 256 + k0 + quad * 8);
#pragma unroll
            for (int ot = 0; ot < 4; ++ot) {
                U4 aw; aw.u = *(const u32x4*)(wlds + (ot * 16 + n16) * WROW + k0 + quad * 8);
                acc[0][ot] = __builtin_amdgcn_mfma_f32_16x16x32_bf16(aw.s, bx0.s, acc[0][ot], 0, 0, 0);
                acc[1][ot] = __builtin_amdgcn_mfma_f32_16x16x32_bf16(aw.s, bx1.s, acc[1][ot], 0, 0, 0);
            }
        }
    }

#pragma unroll
    for (int g = 0; g < 2; ++g) {
        const int m = mrow + g * 16;
        const int s = m >> 3, b = m & 7;
#pragma unroll
        for (int ot = 0; ot < 4; ++ot) {
            int obase = o0 + ot * 16 + quad * 4;   // 4 consecutive o per lane
            if (obase >= NPROJ) continue;
            f32x4 bv = *(const f32x4*)(bias + obase);
            union { unsigned short sh[4]; u32x2 u; } pk;
            pk.sh[0] = f2bf(acc[g][ot].x + bv.x);
            pk.sh[1] = f2bf(acc[g][ot].y + bv.y);
            pk.sh[2] = f2bf(acc[g][ot].z + bv.z);
            pk.sh[3] = f2bf(acc[g][ot].w + bv.w);
            unsigned short* dst;
            if (obase < 256) {
                int h = obase >> 5, d = obase & 31;
                dst = Qb + (((size_t)(h * BATCH + b)) * S_LEN + s) * QD + d;
            } else if (obase < 512) {
                int o2 = obase - 256;
                int h = o2 >> 5, d = o2 & 31;
                dst = Kb + (((size_t)(h * BATCH + b)) * S_LEN + s) * QD + d;
            } else {
                int h = (obase - 512) >> 2;
                dst = Pb + (((size_t)(h * BATCH + b)) * S_LEN + s) * PD;
            }
            *(u32x2*)dst = pk.u;
        }
    }
}

// ---------------------------------------------------------------------------
// Kernel 2: PE[l][ht] = dot(pos[l], Wp[ht]); store REVERSED bf16:
// PEr[h][w][t] = bf16(PE[2046-w][h*4+t])
// ---------------------------------------------------------------------------
__global__ __launch_bounds__(256) void pe_kernel(
    const float* __restrict__ pos, const float* __restrict__ Wp,
    unsigned short* __restrict__ PEr)
{
    int o = blockIdx.x * 256 + threadIdx.x;
    if (o >= LPOS * 32) return;
    int l = o >> 5, ht = o & 31;
    const f32x4* pr = (const f32x4*)(pos + (size_t)l * 192);
    const f32x4* wr = (const f32x4*)(Wp + (size_t)ht * 192);
    float acc = 0.0f;
#pragma unroll 8
    for (int d = 0; d < 48; ++d) {
        f32x4 a = pr[d], w = wr[d];
        acc += a.x * w.x + a.y * w.y + a.z * w.z + a.w * w.w;
    }
    int h = ht >> 2, t = ht & 3, w = 2046 - l;
    PEr[((size_t)h * LPOS + w) * PD + t] = f2bf(acc);
}

// ---------------------------------------------------------------------------
// Kernel 3: scores^T via MFMA + Toeplitz pos-fold + mask + softmax + write.
// Grid (S/16, H*B). Block 256 = 4 waves; wave wv covers j in [wv*256, +256).
// C^T tile: lane holds row i = i0 + (lane&15), cols j0+quad*4+{0..3}.
// PE window staged as PAIRS so each pos A-frag is one aligned ds_read_b128.
// R1/R2 lessons: lb(256,4) spills (-16us); 2-group amortization serializes
// softmax phases (-8us); setprio no help in this 4-wave regime. Keep R0 form.
// ---------------------------------------------------------------------------
__global__ __launch_bounds__(256, 3) void attn_kernel(
    const unsigned short* __restrict__ Qb, const unsigned short* __restrict__ Kb,
    const unsigned short* __restrict__ Pb, const u32x2* __restrict__ PEr,
    const unsigned char* __restrict__ mask, float* __restrict__ out)
{
    __shared__ u32x4 pe_pair[1040];     // {PE4[w], PE4[w+1]} bf16, 16 B/slot
    __shared__ float madd[S_LEN];
    __shared__ float redm[4][16];
    __shared__ float reds[4][16];

    const int hb = blockIdx.y;
    const int h = hb >> 3, b = hb & 7;
    const int i0 = blockIdx.x * 16;
    const int tid = threadIdx.x;
    const int wv = tid >> 6, lane = tid & 63;
    const int n16 = lane & 15, quad = lane >> 4;

    // stage reversed-PE pair window: pe_pair[w] = {PE4r[i0+w], PE4r[i0+w+1]}
    // src[wl+1] stays inside the 128 KB PEr allocation; slots >=1038 unused.
    const u32x2* src = PEr + (size_t)h * LPOS + i0;
    for (int wl = tid; wl < 1039; wl += 256) {
        u32x2 lo = src[wl];
        u32x2 hi = src[wl + 1];
        u32x4 v; v.x = lo.x; v.y = lo.y; v.z = hi.x; v.w = hi.y;
        pe_pair[wl] = v;
    }
    for (int j = tid; j < S_LEN; j += 256)
        madd[j] = mask[b * S_LEN + j] ? -INFINITY : 0.0f;

    // B1: Q fragment (row i0+n16, k = quad*8..+7)
    U4 b1; b1.u = *(const u32x4*)(Qb + ((size_t)hb * S_LEN + i0 + n16) * QD + quad * 8);
    // P row -> sparse B-frags for the two pos MFMAs
    u32x2 p4 = *(const u32x2*)(Pb + ((size_t)hb * S_LEN + i0 + n16) * PD);
    U4 b2, b3;
    b2.u.x = (n16 == 2 * quad)     ? p4.x : 0u;
    b2.u.y = (n16 == 2 * quad)     ? p4.y : 0u;
    b2.u.z = (n16 == 2 * quad + 1) ? p4.x : 0u;
    b2.u.w = (n16 == 2 * quad + 1) ? p4.y : 0u;
    b3.u.x = (n16 == 2 * quad + 8) ? p4.x : 0u;
    b3.u.y = (n16 == 2 * quad + 8) ? p4.y : 0u;
    b3.u.z = (n16 == 2 * quad + 9) ? p4.x : 0u;
    b3.u.w = (n16 == 2 * quad + 9) ? p4.y : 0u;

    __syncthreads();

    f32x4 sc[16];
    const unsigned short* kbase =
        Kb + (size_t)hb * S_LEN * QD + (size_t)(wv * 256 + n16) * QD + quad * 8;
    const int wbase = 1023 - wv * 256 - n16 + 2 * quad;

#pragma unroll
    for (int t = 0; t < 16; ++t) {
        U4 a1; a1.u = *(const u32x4*)(kbase + t * 16 * QD);
        U4 a2; a2.u = pe_pair[wbase - t * 16];
        U4 a3; a3.u = pe_pair[wbase - t * 16 + 8];
        f32x4 acc = {0.0f, 0.0f, 0.0f, 0.0f};
        acc = __builtin_amdgcn_mfma_f32_16x16x32_bf16(a3.s, b3.s, acc, 0, 0, 0);
        acc = __builtin_amdgcn_mfma_f32_16x16x32_bf16(a2.s, b2.s, acc, 0, 0, 0);
        acc = __builtin_amdgcn_mfma_f32_16x16x32_bf16(a1.s, b1.s, acc, 0, 0, 0);
        sc[t] = acc + *(const f32x4*)&madd[wv * 256 + t * 16 + quad * 4];
    }

    // softmax over j for row i = i0 + n16 (lane holds only this row)
    float mx = -INFINITY;
#pragma unroll
    for (int t = 0; t < 16; ++t)
        mx = fmaxf(mx, fmaxf(fmaxf(sc[t].x, sc[t].y), fmaxf(sc[t].z, sc[t].w)));
    mx = fmaxf(mx, __shfl_xor(mx, 16));
    mx = fmaxf(mx, __shfl_xor(mx, 32));
    if (quad == 0) redm[wv][n16] = mx;
    __syncthreads();
    mx = fmaxf(fmaxf(redm[0][n16], redm[1][n16]),
               fmaxf(redm[2][n16], redm[3][n16]));

    float sum = 0.0f;
#pragma unroll
    for (int t = 0; t < 16; ++t) {
        sc[t].x = __expf(sc[t].x - mx);
        sc[t].y = __expf(sc[t].y - mx);
        sc[t].z = __expf(sc[t].z - mx);
        sc[t].w = __expf(sc[t].w - mx);
        sum += sc[t].x + sc[t].y + sc[t].z + sc[t].w;
    }
    sum += __shfl_xor(sum, 16);
    sum += __shfl_xor(sum, 32);
    if (quad == 0) reds[wv][n16] = sum;
    __syncthreads();
    const float tot = reds[0][n16] + reds[1][n16] + reds[2][n16] + reds[3][n16];
    const float inv = 1.0f / tot;

    float* orow = out + ((size_t)hb * S_LEN + i0 + n16) * S_LEN;
#pragma unroll
    for (int t = 0; t < 16; ++t) {
        const int j0 = wv * 256 + t * 16 + quad * 4;
        f32x4 o4 = sc[t] * inv;
        __builtin_nontemporal_store(o4, (f32x4*)(orow + j0));
    }
}

// ---------------------------------------------------------------------------
extern "C" void kernel_launch(void* const* d_in, const int* in_sizes, int n_in,
                              void* d_out, int out_size, void* d_ws, size_t ws_size,
                              hipStream_t stream) {
    (void)in_sizes; (void)n_in; (void)out_size; (void)ws_size;
    const float* x           = (const float*)d_in[0];
    const float* pos_emb     = (const float*)d_in[1];
    const unsigned char* msk = (const unsigned char*)d_in[2];
    const float* in_proj_w   = (const float*)d_in[3];
    const float* in_proj_b   = (const float*)d_in[4];
    const float* linear_posw = (const float*)d_in[5];
    float* out = (float*)d_out;

    char* p = (char*)d_ws;
    unsigned short* Qb  = (unsigned short*)p; p += (size_t)4 << 20;  // 4 MB
    unsigned short* Kb  = (unsigned short*)p; p += (size_t)4 << 20;  // 4 MB
    unsigned short* Pb  = (unsigned short*)p; p += 524288;           // 0.5 MB
    unsigned short* PEr = (unsigned short*)p; p += 131072;           // 128 KB
    unsigned short* Xb  = (unsigned short*)p; p += (size_t)8 << 20;  // 8 MB
    unsigned short* Wb  = (unsigned short*)p; p += 557056;           // ~0.53 MB

    convert_kernel<<<2184, 256, 0, stream>>>(x, in_proj_w, Xb, Wb);
    pe_kernel<<<256, 256, 0, stream>>>(pos_emb, linear_posw, PEr);
    proj_kernel<<<dim3(64, 9), 256, 0, stream>>>(Xb, Wb, in_proj_b, Qb, Kb, Pb);
    attn_kernel<<<dim3(64, 64), 256, 0, stream>>>(Qb, Kb, Pb, (const u32x2*)PEr, msk, out);
}

// Round 4
// 324.192 us; speedup vs baseline: 1.1587x; 1.0764x over previous
//
#include <hip/hip_runtime.h>
#include <math.h>

#define S_LEN 1024
#define BATCH 8
#define NH 8
#define QD 32
#define PD 4
#define EMB 512
#define NPROJ 544
#define LPOS 2047  // 2*S-1

typedef __attribute__((ext_vector_type(8))) short short8;   // 8 bf16 = 4 VGPR
typedef __attribute__((ext_vector_type(4))) float f32x4;
typedef __attribute__((ext_vector_type(4))) unsigned int u32x4;
typedef __attribute__((ext_vector_type(2))) unsigned int u32x2;

union U4 { u32x4 u; short8 s; };

// fp32 -> bf16 round-to-nearest-even
static __device__ inline unsigned short f2bf(float f) {
    unsigned int u = __builtin_bit_cast(unsigned int, f);
    u += 0x7fffu + ((u >> 16) & 1u);
    return (unsigned short)(u >> 16);
}

// ---------------------------------------------------------------------------
// Kernel 0: convert X (4,194,304 f32) and W (278,528 f32) to bf16.
// 2 f32x4 per thread -> one 16B store each.
// ---------------------------------------------------------------------------
#define NXV 1048576   // X float4 count
#define NWV 69632     // W float4 count
__global__ __launch_bounds__(256) void convert_kernel(
    const float* __restrict__ X, const float* __restrict__ W,
    unsigned short* __restrict__ Xb, unsigned short* __restrict__ Wb)
{
    int idx = blockIdx.x * 256 + threadIdx.x;
    int i = idx * 2;   // NXV is even: a pair never straddles the X/W boundary
    const f32x4* src;
    unsigned short* dst;
    if (i < NXV)            { src = (const f32x4*)X; dst = Xb; }
    else if (i < NXV + NWV) { src = (const f32x4*)W; dst = Wb; i -= NXV; }
    else return;
    f32x4 v0 = src[i], v1 = src[i + 1];
    union { unsigned short s[8]; u32x4 u; } pk;
    pk.s[0] = f2bf(v0.x); pk.s[1] = f2bf(v0.y);
    pk.s[2] = f2bf(v0.z); pk.s[3] = f2bf(v0.w);
    pk.s[4] = f2bf(v1.x); pk.s[5] = f2bf(v1.y);
    pk.s[6] = f2bf(v1.z); pk.s[7] = f2bf(v1.w);
    ((u32x4*)dst)[i >> 1] = pk.u;
}

// ---------------------------------------------------------------------------
// Kernel 1: proj^T = W(544x512) @ X^T(512x8192) via MFMA.
// W o-tile staged in LDS (2 k-phases of 256), conflict-free padded rows.
// Block 256 (4 waves): tile 64 o x 128 m; wave wv: 32 m-rows (2 groups of 16),
// 4 o-subtiles -> 8 MFMAs per kk, each LDS aw read feeds 2 MFMAs.
// ---------------------------------------------------------------------------
#define WROW 264   // shorts per LDS W row (256 data + 8 pad): 528 B, 16B-aligned,
                   // row step 132 words -> +4 banks/row -> 2-way on b128 (free)
__global__ __launch_bounds__(256) void proj_kernel(
    const unsigned short* __restrict__ Xb, const unsigned short* __restrict__ Wb,
    const float* __restrict__ bias,
    unsigned short* __restrict__ Qb, unsigned short* __restrict__ Kb,
    unsigned short* __restrict__ Pb)
{
    __shared__ unsigned short wlds[64 * WROW];   // 33,792 B

    const int tid = threadIdx.x;
    const int wv = tid >> 6, lane = tid & 63;
    const int n16 = lane & 15, quad = lane >> 4;
    const int m0 = blockIdx.x * 128, o0 = blockIdx.y * 64;
    const int mrow = m0 + wv * 32 + n16;          // group g adds +16
    const unsigned short* xrow = Xb + (size_t)mrow * EMB;

    f32x4 acc[2][4] = {{{0,0,0,0},{0,0,0,0},{0,0,0,0},{0,0,0,0}},
                       {{0,0,0,0},{0,0,0,0},{0,0,0,0},{0,0,0,0}}};

#pragma unroll
    for (int phase = 0; phase < 2; ++phase) {
        __syncthreads();   // previous phase fully consumed
#pragma unroll
        for (int u = 0; u < 8; ++u) {
            int idx = tid + 256 * u;          // 0..2047
            int r = idx >> 5, c = idx & 31;   // row, 16B chunk within 512B half-row
            int o = o0 + r; if (o > NPROJ - 1) o = NPROJ - 1;
            u32x4 v = *(const u32x4*)(Wb + (size_t)o * EMB + phase * 256 + c * 8);
            *(u32x4*)(wlds + r * WROW + c * 8) = v;
        }
        __syncthreads();
#pragma unroll
        for (int kk = 0; kk < 8; ++kk) {
            const int k0 = kk * 32;
            U4 bx0; bx0.u = *(const u32x4*)(xrow + phase * 256 + k0 + quad * 8);
            U4 bx1; bx1.u = *(const u32x4*)(xrow + (size_t)16 * EMB + phase * 256 + k0 + quad * 8);
#pragma unroll
            for (int ot = 0; ot < 4; ++ot) {
                U4 aw; aw.u = *(const u32x4*)(wlds + (ot * 16 + n16) * WROW + k0 + quad * 8);
                acc[0][ot] = __builtin_amdgcn_mfma_f32_16x16x32_bf16(aw.s, bx0.s, acc[0][ot], 0, 0, 0);
                acc[1][ot] = __builtin_amdgcn_mfma_f32_16x16x32_bf16(aw.s, bx1.s, acc[1][ot], 0, 0, 0);
            }
        }
    }

#pragma unroll
    for (int g = 0; g < 2; ++g) {
        const int m = mrow + g * 16;
        const int s = m >> 3, b = m & 7;
#pragma unroll
        for (int ot = 0; ot < 4; ++ot) {
            int obase = o0 + ot * 16 + quad * 4;   // 4 consecutive o per lane
            if (obase >= NPROJ) continue;
            f32x4 bv = *(const f32x4*)(bias + obase);
            union { unsigned short sh[4]; u32x2 u; } pk;
            pk.sh[0] = f2bf(acc[g][ot].x + bv.x);
            pk.sh[1] = f2bf(acc[g][ot].y + bv.y);
            pk.sh[2] = f2bf(acc[g][ot].z + bv.z);
            pk.sh[3] = f2bf(acc[g][ot].w + bv.w);
            unsigned short* dst;
            if (obase < 256) {
                int h = obase >> 5, d = obase & 31;
                dst = Qb + (((size_t)(h * BATCH + b)) * S_LEN + s) * QD + d;
            } else if (obase < 512) {
                int o2 = obase - 256;
                int h = o2 >> 5, d = o2 & 31;
                dst = Kb + (((size_t)(h * BATCH + b)) * S_LEN + s) * QD + d;
            } else {
                int h = (obase - 512) >> 2;
                dst = Pb + (((size_t)(h * BATCH + b)) * S_LEN + s) * PD;
            }
            *(u32x2*)dst = pk.u;
        }
    }
}

// ---------------------------------------------------------------------------
// Kernel 2: PE[l][ht] = dot(pos[l], Wp[ht]); store REVERSED bf16:
// PEr[h][w][t] = bf16(PE[2046-w][h*4+t])
// ---------------------------------------------------------------------------
__global__ __launch_bounds__(256) void pe_kernel(
    const float* __restrict__ pos, const float* __restrict__ Wp,
    unsigned short* __restrict__ PEr)
{
    int o = blockIdx.x * 256 + threadIdx.x;
    if (o >= LPOS * 32) return;
    int l = o >> 5, ht = o & 31;
    const f32x4* pr = (const f32x4*)(pos + (size_t)l * 192);
    const f32x4* wr = (const f32x4*)(Wp + (size_t)ht * 192);
    float acc = 0.0f;
#pragma unroll 8
    for (int d = 0; d < 48; ++d) {
        f32x4 a = pr[d], w = wr[d];
        acc += a.x * w.x + a.y * w.y + a.z * w.z + a.w * w.w;
    }
    int h = ht >> 2, t = ht & 3, w = 2046 - l;
    PEr[((size_t)h * LPOS + w) * PD + t] = f2bf(acc);
}

// ---------------------------------------------------------------------------
// Kernel 3: scores^T via MFMA + Toeplitz pos-fold + mask + softmax + write.
// Grid (S/16, H*B). Block 256 = 4 waves; wave wv covers j in [wv*256, +256).
// C^T tile: lane holds row i = i0 + (lane&15), cols j0+quad*4+{0..3}.
// PE window staged as PAIRS so each pos A-frag is one aligned ds_read_b128.
// R4 change: store via wave-private LDS transpose. Direct C^T stores write
// 16 x 64B segments at 4KB stride per instr (poor HBM burst locality);
// transposed stores write 4 rows x 256B contiguous per instr. Rotation
// phys=(logical+4*row)&63 keeps every b128 LDS access at the 8-word/bank
// floor (conflict-free). Values bit-identical.
// ---------------------------------------------------------------------------
__global__ __launch_bounds__(256, 3) void attn_kernel(
    const unsigned short* __restrict__ Qb, const unsigned short* __restrict__ Kb,
    const unsigned short* __restrict__ Pb, const u32x2* __restrict__ PEr,
    const unsigned char* __restrict__ mask, float* __restrict__ out)
{
    __shared__ u32x4 pe_pair[1040];     // {PE4[w], PE4[w+1]} bf16, 16 B/slot
    __shared__ float madd[S_LEN];
    __shared__ float redm[4][16];
    __shared__ float reds[4][16];
    __shared__ float tbuf[4 * 1024];    // 16 KB: per-wave 16 rows x 64 words

    const int hb = blockIdx.y;
    const int h = hb >> 3, b = hb & 7;
    const int i0 = blockIdx.x * 16;
    const int tid = threadIdx.x;
    const int wv = tid >> 6, lane = tid & 63;
    const int n16 = lane & 15, quad = lane >> 4;

    // stage reversed-PE pair window: pe_pair[w] = {PE4r[i0+w], PE4r[i0+w+1]}
    // src[wl+1] stays inside the 128 KB PEr allocation; slots >=1038 unused.
    const u32x2* src = PEr + (size_t)h * LPOS + i0;
    for (int wl = tid; wl < 1039; wl += 256) {
        u32x2 lo = src[wl];
        u32x2 hi = src[wl + 1];
        u32x4 v; v.x = lo.x; v.y = lo.y; v.z = hi.x; v.w = hi.y;
        pe_pair[wl] = v;
    }
    for (int j = tid; j < S_LEN; j += 256)
        madd[j] = mask[b * S_LEN + j] ? -INFINITY : 0.0f;

    // B1: Q fragment (row i0+n16, k = quad*8..+7)
    U4 b1; b1.u = *(const u32x4*)(Qb + ((size_t)hb * S_LEN + i0 + n16) * QD + quad * 8);
    // P row -> sparse B-frags for the two pos MFMAs
    u32x2 p4 = *(const u32x2*)(Pb + ((size_t)hb * S_LEN + i0 + n16) * PD);
    U4 b2, b3;
    b2.u.x = (n16 == 2 * quad)     ? p4.x : 0u;
    b2.u.y = (n16 == 2 * quad)     ? p4.y : 0u;
    b2.u.z = (n16 == 2 * quad + 1) ? p4.x : 0u;
    b2.u.w = (n16 == 2 * quad + 1) ? p4.y : 0u;
    b3.u.x = (n16 == 2 * quad + 8) ? p4.x : 0u;
    b3.u.y = (n16 == 2 * quad + 8) ? p4.y : 0u;
    b3.u.z = (n16 == 2 * quad + 9) ? p4.x : 0u;
    b3.u.w = (n16 == 2 * quad + 9) ? p4.y : 0u;

    __syncthreads();

    f32x4 sc[16];
    const unsigned short* kbase =
        Kb + (size_t)hb * S_LEN * QD + (size_t)(wv * 256 + n16) * QD + quad * 8;
    const int wbase = 1023 - wv * 256 - n16 + 2 * quad;

#pragma unroll
    for (int t = 0; t < 16; ++t) {
        U4 a1; a1.u = *(const u32x4*)(kbase + t * 16 * QD);
        U4 a2; a2.u = pe_pair[wbase - t * 16];
        U4 a3; a3.u = pe_pair[wbase - t * 16 + 8];
        f32x4 acc = {0.0f, 0.0f, 0.0f, 0.0f};
        acc = __builtin_amdgcn_mfma_f32_16x16x32_bf16(a3.s, b3.s, acc, 0, 0, 0);
        acc = __builtin_amdgcn_mfma_f32_16x16x32_bf16(a2.s, b2.s, acc, 0, 0, 0);
        acc = __builtin_amdgcn_mfma_f32_16x16x32_bf16(a1.s, b1.s, acc, 0, 0, 0);
        sc[t] = acc + *(const f32x4*)&madd[wv * 256 + t * 16 + quad * 4];
    }

    // softmax over j for row i = i0 + n16 (lane holds only this row)
    float mx = -INFINITY;
#pragma unroll
    for (int t = 0; t < 16; ++t)
        mx = fmaxf(mx, fmaxf(fmaxf(sc[t].x, sc[t].y), fmaxf(sc[t].z, sc[t].w)));
    mx = fmaxf(mx, __shfl_xor(mx, 16));
    mx = fmaxf(mx, __shfl_xor(mx, 32));
    if (quad == 0) redm[wv][n16] = mx;
    __syncthreads();
    mx = fmaxf(fmaxf(redm[0][n16], redm[1][n16]),
               fmaxf(redm[2][n16], redm[3][n16]));

    float sum = 0.0f;
#pragma unroll
    for (int t = 0; t < 16; ++t) {
        sc[t].x = __expf(sc[t].x - mx);
        sc[t].y = __expf(sc[t].y - mx);
        sc[t].z = __expf(sc[t].z - mx);
        sc[t].w = __expf(sc[t].w - mx);
        sum += sc[t].x + sc[t].y + sc[t].z + sc[t].w;
    }
    sum += __shfl_xor(sum, 16);
    sum += __shfl_xor(sum, 32);
    if (quad == 0) reds[wv][n16] = sum;
    __syncthreads();
    const float tot = reds[0][n16] + reds[1][n16] + reds[2][n16] + reds[3][n16];
    const float inv = 1.0f / tot;

    // --- transposed store: chunk = 4 t's = 64 consecutive j ---
    // write: lane (n16,quad) puts sc[c*4+tl]*inv at row n16,
    //        logical word tl*16+quad*4, phys = (logical + 4*row) & 63.
    // read:  lane l covers row r = (l>>4)+4*ii, logical (l&15)*4
    //        -> each store instr = 4 rows x 256B contiguous.
    float* wbuf = tbuf + wv * 1024;
    const int i_out_base = (int)((size_t)hb * S_LEN + i0);
#pragma unroll
    for (int c = 0; c < 4; ++c) {
#pragma unroll
        for (int tl = 0; tl < 4; ++tl) {
            f32x4 o4 = sc[c * 4 + tl] * inv;
            int phys = ((tl * 16 + quad * 4) + 4 * n16) & 63;
            *(f32x4*)&wbuf[n16 * 64 + phys] = o4;
        }
#pragma unroll
        for (int ii = 0; ii < 4; ++ii) {
            int r = (lane >> 4) + 4 * ii;
            int phys = (((lane & 15) * 4) + 4 * r) & 63;
            f32x4 v = *(const f32x4*)&wbuf[r * 64 + phys];
            float* dst = out + (size_t)(i_out_base + r) * S_LEN
                         + wv * 256 + c * 64 + (lane & 15) * 4;
            __builtin_nontemporal_store(v, (f32x4*)dst);
        }
    }
}

// ---------------------------------------------------------------------------
extern "C" void kernel_launch(void* const* d_in, const int* in_sizes, int n_in,
                              void* d_out, int out_size, void* d_ws, size_t ws_size,
                              hipStream_t stream) {
    (void)in_sizes; (void)n_in; (void)out_size; (void)ws_size;
    const float* x           = (const float*)d_in[0];
    const float* pos_emb     = (const float*)d_in[1];
    const unsigned char* msk = (const unsigned char*)d_in[2];
    const float* in_proj_w   = (const float*)d_in[3];
    const float* in_proj_b   = (const float*)d_in[4];
    const float* linear_posw = (const float*)d_in[5];
    float* out = (float*)d_out;

    char* p = (char*)d_ws;
    unsigned short* Qb  = (unsigned short*)p; p += (size_t)4 << 20;  // 4 MB
    unsigned short* Kb  = (unsigned short*)p; p += (size_t)4 << 20;  // 4 MB
    unsigned short* Pb  = (unsigned short*)p; p += 524288;           // 0.5 MB
    unsigned short* PEr = (unsigned short*)p; p += 131072;           // 128 KB
    unsigned short* Xb  = (unsigned short*)p; p += (size_t)8 << 20;  // 8 MB
    unsigned short* Wb  = (unsigned short*)p; p += 557056;           // ~0.53 MB

    convert_kernel<<<2184, 256, 0, stream>>>(x, in_proj_w, Xb, Wb);
    pe_kernel<<<256, 256, 0, stream>>>(pos_emb, linear_posw, PEr);
    proj_kernel<<<dim3(64, 9), 256, 0, stream>>>(Xb, Wb, in_proj_b, Qb, Kb, Pb);
    attn_kernel<<<dim3(64, 64), 256, 0, stream>>>(Qb, Kb, Pb, (const u32x2*)PEr, msk, out);
}

// Round 5
// 322.096 us; speedup vs baseline: 1.1662x; 1.0065x over previous
//
#include <hip/hip_runtime.h>
#include <math.h>

#define S_LEN 1024
#define BATCH 8
#define NH 8
#define QD 32
#define PD 4
#define EMB 512
#define NPROJ 544
#define LPOS 2047  // 2*S-1

typedef __attribute__((ext_vector_type(8))) short short8;   // 8 bf16 = 4 VGPR
typedef __attribute__((ext_vector_type(4))) float f32x4;
typedef __attribute__((ext_vector_type(4))) unsigned int u32x4;
typedef __attribute__((ext_vector_type(2))) unsigned int u32x2;

union U4 { u32x4 u; short8 s; };

// fp32 -> bf16 round-to-nearest-even
static __device__ inline unsigned short f2bf(float f) {
    unsigned int u = __builtin_bit_cast(unsigned int, f);
    u += 0x7fffu + ((u >> 16) & 1u);
    return (unsigned short)(u >> 16);
}

// ---------------------------------------------------------------------------
// Kernel 0: convert X (4,194,304 f32) and W (278,528 f32) to bf16.
// 2 f32x4 per thread -> one 16B store each.
// ---------------------------------------------------------------------------
#define NXV 1048576   // X float4 count
#define NWV 69632     // W float4 count
__global__ __launch_bounds__(256) void convert_kernel(
    const float* __restrict__ X, const float* __restrict__ W,
    unsigned short* __restrict__ Xb, unsigned short* __restrict__ Wb)
{
    int idx = blockIdx.x * 256 + threadIdx.x;
    int i = idx * 2;   // NXV is even: a pair never straddles the X/W boundary
    const f32x4* src;
    unsigned short* dst;
    if (i < NXV)            { src = (const f32x4*)X; dst = Xb; }
    else if (i < NXV + NWV) { src = (const f32x4*)W; dst = Wb; i -= NXV; }
    else return;
    f32x4 v0 = src[i], v1 = src[i + 1];
    union { unsigned short s[8]; u32x4 u; } pk;
    pk.s[0] = f2bf(v0.x); pk.s[1] = f2bf(v0.y);
    pk.s[2] = f2bf(v0.z); pk.s[3] = f2bf(v0.w);
    pk.s[4] = f2bf(v1.x); pk.s[5] = f2bf(v1.y);
    pk.s[6] = f2bf(v1.z); pk.s[7] = f2bf(v1.w);
    ((u32x4*)dst)[i >> 1] = pk.u;
}

// ---------------------------------------------------------------------------
// Kernel 1: proj^T = W(544x512) @ X^T(512x8192) via MFMA.
// W o-tile staged in LDS (2 k-phases of 256), conflict-free padded rows.
// Block 256 (4 waves): tile 64 o x 128 m; wave wv: 32 m-rows (2 groups of 16),
// 4 o-subtiles -> 8 MFMAs per kk, each LDS aw read feeds 2 MFMAs.
// ---------------------------------------------------------------------------
#define WROW 264   // shorts per LDS W row (256 data + 8 pad): 528 B, 16B-aligned,
                   // row step 132 words -> +4 banks/row -> 2-way on b128 (free)
__global__ __launch_bounds__(256) void proj_kernel(
    const unsigned short* __restrict__ Xb, const unsigned short* __restrict__ Wb,
    const float* __restrict__ bias,
    unsigned short* __restrict__ Qb, unsigned short* __restrict__ Kb,
    unsigned short* __restrict__ Pb)
{
    __shared__ unsigned short wlds[64 * WROW];   // 33,792 B

    const int tid = threadIdx.x;
    const int wv = tid >> 6, lane = tid & 63;
    const int n16 = lane & 15, quad = lane >> 4;
    const int m0 = blockIdx.x * 128, o0 = blockIdx.y * 64;
    const int mrow = m0 + wv * 32 + n16;          // group g adds +16
    const unsigned short* xrow = Xb + (size_t)mrow * EMB;

    f32x4 acc[2][4] = {{{0,0,0,0},{0,0,0,0},{0,0,0,0},{0,0,0,0}},
                       {{0,0,0,0},{0,0,0,0},{0,0,0,0},{0,0,0,0}}};

#pragma unroll
    for (int phase = 0; phase < 2; ++phase) {
        __syncthreads();   // previous phase fully consumed
#pragma unroll
        for (int u = 0; u < 8; ++u) {
            int idx = tid + 256 * u;          // 0..2047
            int r = idx >> 5, c = idx & 31;   // row, 16B chunk within 512B half-row
            int o = o0 + r; if (o > NPROJ - 1) o = NPROJ - 1;
            u32x4 v = *(const u32x4*)(Wb + (size_t)o * EMB + phase * 256 + c * 8);
            *(u32x4*)(wlds + r * WROW + c * 8) = v;
        }
        __syncthreads();
#pragma unroll
        for (int kk = 0; kk < 8; ++kk) {
            const int k0 = kk * 32;
            U4 bx0; bx0.u = *(const u32x4*)(xrow + phase * 256 + k0 + quad * 8);
            U4 bx1; bx1.u = *(const u32x4*)(xrow + (size_t)16 * EMB + phase * 256 + k0 + quad * 8);
#pragma unroll
            for (int ot = 0; ot < 4; ++ot) {
                U4 aw; aw.u = *(const u32x4*)(wlds + (ot * 16 + n16) * WROW + k0 + quad * 8);
                acc[0][ot] = __builtin_amdgcn_mfma_f32_16x16x32_bf16(aw.s, bx0.s, acc[0][ot], 0, 0, 0);
                acc[1][ot] = __builtin_amdgcn_mfma_f32_16x16x32_bf16(aw.s, bx1.s, acc[1][ot], 0, 0, 0);
            }
        }
    }

#pragma unroll
    for (int g = 0; g < 2; ++g) {
        const int m = mrow + g * 16;
        const int s = m >> 3, b = m & 7;
#pragma unroll
        for (int ot = 0; ot < 4; ++ot) {
            int obase = o0 + ot * 16 + quad * 4;   // 4 consecutive o per lane
            if (obase >= NPROJ) continue;
            f32x4 bv = *(const f32x4*)(bias + obase);
            union { unsigned short sh[4]; u32x2 u; } pk;
            pk.sh[0] = f2bf(acc[g][ot].x + bv.x);
            pk.sh[1] = f2bf(acc[g][ot].y + bv.y);
            pk.sh[2] = f2bf(acc[g][ot].z + bv.z);
            pk.sh[3] = f2bf(acc[g][ot].w + bv.w);
            unsigned short* dst;
            if (obase < 256) {
                int h = obase >> 5, d = obase & 31;
                dst = Qb + (((size_t)(h * BATCH + b)) * S_LEN + s) * QD + d;
            } else if (obase < 512) {
                int o2 = obase - 256;
                int h = o2 >> 5, d = o2 & 31;
                dst = Kb + (((size_t)(h * BATCH + b)) * S_LEN + s) * QD + d;
            } else {
                int h = (obase - 512) >> 2;
                dst = Pb + (((size_t)(h * BATCH + b)) * S_LEN + s) * PD;
            }
            *(u32x2*)dst = pk.u;
        }
    }
}

// ---------------------------------------------------------------------------
// Kernel 2: PE[l][ht] = dot(pos[l], Wp[ht]); store REVERSED bf16:
// PEr[h][w][t] = bf16(PE[2046-w][h*4+t])
// ---------------------------------------------------------------------------
__global__ __launch_bounds__(256) void pe_kernel(
    const float* __restrict__ pos, const float* __restrict__ Wp,
    unsigned short* __restrict__ PEr)
{
    int o = blockIdx.x * 256 + threadIdx.x;
    if (o >= LPOS * 32) return;
    int l = o >> 5, ht = o & 31;
    const f32x4* pr = (const f32x4*)(pos + (size_t)l * 192);
    const f32x4* wr = (const f32x4*)(Wp + (size_t)ht * 192);
    float acc = 0.0f;
#pragma unroll 8
    for (int d = 0; d < 48; ++d) {
        f32x4 a = pr[d], w = wr[d];
        acc += a.x * w.x + a.y * w.y + a.z * w.z + a.w * w.w;
    }
    int h = ht >> 2, t = ht & 3, w = 2046 - l;
    PEr[((size_t)h * LPOS + w) * PD + t] = f2bf(acc);
}

// ---------------------------------------------------------------------------
// Kernel 3: scores^T via MFMA + Toeplitz pos-fold + mask + softmax + write.
// Grid (S/16, H*B). Block 256 = 4 waves; wave wv covers j in [wv*256, +256).
// C^T tile: lane holds row i = i0 + (lane&15), cols j0+quad*4+{0..3}.
// R5 changes vs R4 (confirmed store-pattern theory, push further):
//  - transpose chunk 64 -> 128 j: each store instr writes 2 x 512B contiguous
//    segments (R4: 4 x 256B). Same LDS/store instruction counts.
//  - tbuf (32 KB) ALIASES pe_pair: pe_pair is dead after the t-loop, and the
//    softmax barrier orders every pe_pair read before any tbuf write. Each
//    wave only touches its own 8 KB tbuf region (no cross-wave sync needed).
//    Total LDS 37.4 KB (< R4's 37.9).
//  - single-barrier softmax: exp against WAVE-LOCAL max pre-barrier; publish
//    (m_w, s_w); fold exp(m_w-m)/tot into the store-time scale.
// Rotation phys=(logical+4*row)&127 keeps both LDS phases at the 8-word/bank
// floor (write: (quad+n16) mod 8 uniform; read: (lane&31 + r) mod 8 uniform).
// ---------------------------------------------------------------------------
__global__ __launch_bounds__(256, 3) void attn_kernel(
    const unsigned short* __restrict__ Qb, const unsigned short* __restrict__ Kb,
    const unsigned short* __restrict__ Pb, const u32x2* __restrict__ PEr,
    const unsigned char* __restrict__ mask, float* __restrict__ out)
{
    __shared__ u32x4 smem[2048];        // 32 KB union: pe_pair (16.6 KB) | tbuf
    __shared__ float madd[S_LEN];
    __shared__ float redm[4][16];
    __shared__ float reds[4][16];
    u32x4* pe_pair = smem;              // [1040] {PE4[w], PE4[w+1]}, 16 B/slot
    float* tbuf = (float*)smem;         // [4][16][128] per-wave transpose buf

    const int hb = blockIdx.y;
    const int h = hb >> 3, b = hb & 7;
    const int i0 = blockIdx.x * 16;
    const int tid = threadIdx.x;
    const int wv = tid >> 6, lane = tid & 63;
    const int n16 = lane & 15, quad = lane >> 4;

    // stage reversed-PE pair window: pe_pair[w] = {PE4r[i0+w], PE4r[i0+w+1]}
    // src[wl+1] stays inside the 128 KB PEr allocation; slots >=1038 unused.
    const u32x2* src = PEr + (size_t)h * LPOS + i0;
    for (int wl = tid; wl < 1039; wl += 256) {
        u32x2 lo = src[wl];
        u32x2 hi = src[wl + 1];
        u32x4 v; v.x = lo.x; v.y = lo.y; v.z = hi.x; v.w = hi.y;
        pe_pair[wl] = v;
    }
    for (int j = tid; j < S_LEN; j += 256)
        madd[j] = mask[b * S_LEN + j] ? -INFINITY : 0.0f;

    // B1: Q fragment (row i0+n16, k = quad*8..+7)
    U4 b1; b1.u = *(const u32x4*)(Qb + ((size_t)hb * S_LEN + i0 + n16) * QD + quad * 8);
    // P row -> sparse B-frags for the two pos MFMAs
    u32x2 p4 = *(const u32x2*)(Pb + ((size_t)hb * S_LEN + i0 + n16) * PD);
    U4 b2, b3;
    b2.u.x = (n16 == 2 * quad)     ? p4.x : 0u;
    b2.u.y = (n16 == 2 * quad)     ? p4.y : 0u;
    b2.u.z = (n16 == 2 * quad + 1) ? p4.x : 0u;
    b2.u.w = (n16 == 2 * quad + 1) ? p4.y : 0u;
    b3.u.x = (n16 == 2 * quad + 8) ? p4.x : 0u;
    b3.u.y = (n16 == 2 * quad + 8) ? p4.y : 0u;
    b3.u.z = (n16 == 2 * quad + 9) ? p4.x : 0u;
    b3.u.w = (n16 == 2 * quad + 9) ? p4.y : 0u;

    __syncthreads();

    f32x4 sc[16];
    const unsigned short* kbase =
        Kb + (size_t)hb * S_LEN * QD + (size_t)(wv * 256 + n16) * QD + quad * 8;
    const int wbase = 1023 - wv * 256 - n16 + 2 * quad;

#pragma unroll
    for (int t = 0; t < 16; ++t) {
        U4 a1; a1.u = *(const u32x4*)(kbase + t * 16 * QD);
        U4 a2; a2.u = pe_pair[wbase - t * 16];
        U4 a3; a3.u = pe_pair[wbase - t * 16 + 8];
        f32x4 acc = {0.0f, 0.0f, 0.0f, 0.0f};
        acc = __builtin_amdgcn_mfma_f32_16x16x32_bf16(a3.s, b3.s, acc, 0, 0, 0);
        acc = __builtin_amdgcn_mfma_f32_16x16x32_bf16(a2.s, b2.s, acc, 0, 0, 0);
        acc = __builtin_amdgcn_mfma_f32_16x16x32_bf16(a1.s, b1.s, acc, 0, 0, 0);
        sc[t] = acc + *(const f32x4*)&madd[wv * 256 + t * 16 + quad * 4];
    }

    // --- single-barrier softmax ---
    // wave-local row max (this wave's 256 j of row i0+n16)
    float mxw = -INFINITY;
#pragma unroll
    for (int t = 0; t < 16; ++t)
        mxw = fmaxf(mxw, fmaxf(fmaxf(sc[t].x, sc[t].y), fmaxf(sc[t].z, sc[t].w)));
    mxw = fmaxf(mxw, __shfl_xor(mxw, 16));
    mxw = fmaxf(mxw, __shfl_xor(mxw, 32));

    // exp against local max + local sum (pre-barrier, off the x-wave path)
    float sum = 0.0f;
#pragma unroll
    for (int t = 0; t < 16; ++t) {
        sc[t].x = __expf(sc[t].x - mxw);
        sc[t].y = __expf(sc[t].y - mxw);
        sc[t].z = __expf(sc[t].z - mxw);
        sc[t].w = __expf(sc[t].w - mxw);
        sum += sc[t].x + sc[t].y + sc[t].z + sc[t].w;
    }
    sum += __shfl_xor(sum, 16);
    sum += __shfl_xor(sum, 32);
    if (quad == 0) { redm[wv][n16] = mxw; reds[wv][n16] = sum; }
    __syncthreads();   // also orders all pe_pair reads before tbuf writes

    const float m0_ = redm[0][n16], m1_ = redm[1][n16];
    const float m2_ = redm[2][n16], m3_ = redm[3][n16];
    const float m = fmaxf(fmaxf(m0_, m1_), fmaxf(m2_, m3_));
    const float tot = reds[0][n16] * __expf(m0_ - m)
                    + reds[1][n16] * __expf(m1_ - m)
                    + reds[2][n16] * __expf(m2_ - m)
                    + reds[3][n16] * __expf(m3_ - m);
    const float scale = __expf(mxw - m) / tot;

    // --- transposed store: chunk = 8 t's = 128 consecutive j ---
    // write: lane (n16,quad) puts sc[c*8+tl]*scale at row n16,
    //        logical word tl*16+quad*4, phys = (logical + 4*row) & 127.
    // read:  lane l covers row r = (l>>5)+2*ii, logical (l&31)*4
    //        -> each store instr = 2 rows x 512B contiguous.
    float* wbuf = tbuf + wv * 2048;     // 8 KB per wave: 16 rows x 128 words
    const int i_out_base = (int)((size_t)hb * S_LEN + i0);
#pragma unroll
    for (int c = 0; c < 2; ++c) {
#pragma unroll
        for (int tl = 0; tl < 8; ++tl) {
            f32x4 o4 = sc[c * 8 + tl] * scale;
            int phys = ((tl * 16 + quad * 4) + 4 * n16) & 127;
            *(f32x4*)&wbuf[n16 * 128 + phys] = o4;
        }
#pragma unroll
        for (int ii = 0; ii < 8; ++ii) {
            int r = (lane >> 5) + 2 * ii;
            int phys = (((lane & 31) * 4) + 4 * r) & 127;
            f32x4 v = *(const f32x4*)&wbuf[r * 128 + phys];
            float* dst = out + (size_t)(i_out_base + r) * S_LEN
                         + wv * 256 + c * 128 + (lane & 31) * 4;
            __builtin_nontemporal_store(v, (f32x4*)dst);
        }
    }
}

// ---------------------------------------------------------------------------
extern "C" void kernel_launch(void* const* d_in, const int* in_sizes, int n_in,
                              void* d_out, int out_size, void* d_ws, size_t ws_size,
                              hipStream_t stream) {
    (void)in_sizes; (void)n_in; (void)out_size; (void)ws_size;
    const float* x           = (const float*)d_in[0];
    const float* pos_emb     = (const float*)d_in[1];
    const unsigned char* msk = (const unsigned char*)d_in[2];
    const float* in_proj_w   = (const float*)d_in[3];
    const float* in_proj_b   = (const float*)d_in[4];
    const float* linear_posw = (const float*)d_in[5];
    float* out = (float*)d_out;

    char* p = (char*)d_ws;
    unsigned short* Qb  = (unsigned short*)p; p += (size_t)4 << 20;  // 4 MB
    unsigned short* Kb  = (unsigned short*)p; p += (size_t)4 << 20;  // 4 MB
    unsigned short* Pb  = (unsigned short*)p; p += 524288;           // 0.5 MB
    unsigned short* PEr = (unsigned short*)p; p += 131072;           // 128 KB
    unsigned short* Xb  = (unsigned short*)p; p += (size_t)8 << 20;  // 8 MB
    unsigned short* Wb  = (unsigned short*)p; p += 557056;           // ~0.53 MB

    convert_kernel<<<2184, 256, 0, stream>>>(x, in_proj_w, Xb, Wb);
    pe_kernel<<<256, 256, 0, stream>>>(pos_emb, linear_posw, PEr);
    proj_kernel<<<dim3(64, 9), 256, 0, stream>>>(Xb, Wb, in_proj_b, Qb, Kb, Pb);
    attn_kernel<<<dim3(64, 64), 256, 0, stream>>>(Qb, Kb, Pb, (const u32x2*)PEr, msk, out);
}